// Round 3
// baseline (131.014 us; speedup 1.0000x reference)
//
#include <hip/hip_runtime.h>

#define NQ_ 30000
#define NC_ 16
#define C_  128
#define NS_ 8192
#define QB  16
#define NBLK (NQ_/QB)   // 1875

typedef __attribute__((ext_vector_type(4))) float  f32x4;
typedef __attribute__((ext_vector_type(4))) short  s16x4;
typedef __attribute__((ext_vector_type(8))) short  s16x8;

// workspace layout (float offsets)
#define WS_PART  0         // 16 cls * 16 chunks * 128 = 32768
#define WS_PCNT  32768     // 256
#define WS_T     33024     // 2048  (protos @ Wp + b1)
#define WS_PACK  35072     // shorts from here: W2frag[16384] Wqfrag[16384] pnfrag[2048]

// LDS-only barrier: does NOT drain vmcnt -> global stores stay in flight
#define BAR_LGKM() asm volatile("s_waitcnt lgkmcnt(0)\ns_barrier" ::: "memory")

__device__ inline short f2bf(float x){           // round-to-nearest-even bf16
  unsigned u = __float_as_uint(x);
  u += 0x7fffu + ((u >> 16) & 1u);
  return (short)(u >> 16);
}

// ---- prototypes: deterministic fixed-order partial sums ----
__global__ __launch_bounds__(128) void proto_part(const float* __restrict__ sf,
                                                  const int* __restrict__ lbl,
                                                  float* __restrict__ ws){
  const int cls = blockIdx.x >> 4;
  const int ch  = blockIdx.x & 15;
  const int c   = threadIdx.x;
  const int r0  = ch * (NS_/16);
  float s = 0.f; int cnt = 0;
  #pragma unroll 4
  for (int r = r0; r < r0 + NS_/16; ++r){
    if (lbl[r] == cls){ s += sf[(size_t)r*C_ + c]; ++cnt; }
  }
  ws[WS_PART + (cls*16 + ch)*C_ + c] = s;
  if (c == 0) ws[WS_PCNT + cls*16 + ch] = (float)cnt;
}

// ---- fused: finalize protos + pn + tmat + weight pack (one block, 512 thr) ----
__global__ __launch_bounds__(512) void prep2(const float* __restrict__ W1,
                                             const float* __restrict__ b1,
                                             const float* __restrict__ W2,
                                             float* __restrict__ ws){
  __shared__ float p[NC_][C_];
  __shared__ float pn[NC_][C_];
  __shared__ float rn[NC_];
  __shared__ float cl[NC_];
  const int t = threadIdx.x;
  if (t < NC_){
    float s = 0.f;
    #pragma unroll
    for (int ch = 0; ch < 16; ++ch) s += ws[WS_PCNT + t*16 + ch];
    cl[t] = s;
  }
  __syncthreads();
  #pragma unroll
  for (int j = 0; j < 4; ++j){
    const int idx = j*512 + t, n = idx >> 7, c = idx & 127;
    float s = 0.f;
    #pragma unroll
    for (int ch = 0; ch < 16; ++ch) s += ws[WS_PART + (n*16 + ch)*C_ + c];
    const float cv = cl[n];
    p[n][c] = (cv > 0.f) ? s / fmaxf(cv, 1.f) : 0.f;
  }
  __syncthreads();
  if (t < NC_){
    float s = 0.f;
    #pragma unroll 4
    for (int c = 0; c < C_; ++c) s = fmaf(p[t][c], p[t][c], s);
    rn[t] = 1.f / fmaxf(sqrtf(s), 1e-8f);
  }
  __syncthreads();
  #pragma unroll
  for (int j = 0; j < 4; ++j){
    const int idx = j*512 + t, n = idx >> 7, c = idx & 127;
    pn[n][c] = p[n][c] * rn[n];
  }
  // t-matrix: protos @ Wp + b1
  #pragma unroll
  for (int j = 0; j < 4; ++j){
    const int idx = j*512 + t, n = idx >> 7, h = idx & 127;
    float acc = b1[h];
    #pragma unroll 4
    for (int c = 0; c < C_; ++c) acc = fmaf(p[n][c], W1[(C_ + c)*C_ + h], acc);
    ws[WS_T + idx] = acc;
  }
  __syncthreads();   // pn visible for pack
  short* packo = (short*)(ws + WS_PACK);
  for (int g = t; g < 34816; g += 512){
    const int gg = g & 16383, i = gg & 7, ln = (gg >> 3) & 63, ks = (gg >> 9) & 3, wvv = gg >> 11;
    const int k = ks*32 + ((ln >> 4) & 3)*8 + i, col = wvv*16 + (ln & 15);
    float v;
    if (g < 16384)      v = W2[k*C_ + col];
    else if (g < 32768) v = W1[k*C_ + col];     // Wq = W1 rows [0,128)
    else                v = pn[ln & 15][k];     // pn^T B-frags (wv==0 only)
    packo[g] = f2bf(v);
  }
}

// ---- fused main ----
__global__ __launch_bounds__(512, 4) void fused_main(const float* __restrict__ qfeat,
                                                     const float* __restrict__ W1,
                                                     const float* __restrict__ b2,
                                                     const float* __restrict__ ws,
                                                     float* __restrict__ out){
  __shared__ __align__(16) char un[16384];   // qfs[16][132] f32, then hfrag dbuf 2x8192B
  __shared__ float qw[QB][132];
  __shared__ float tl16[NC_][132];
  __shared__ float cosl[QB][NC_];
  __shared__ float rqn[QB];
  __shared__ float wcl[C_];

  float (*qfs)[132] = (float(*)[132])un;

  const int t    = threadIdx.x;
  const int lane = t & 63;
  const int wv   = t >> 6;
  const int qbase = blockIdx.x * QB;
  float* out_cos = out + (size_t)NQ_ * NC_ * C_;
  const short* pack = (const short*)(ws + WS_PACK);

  // stage qf (16x128), t-matrix, Wc — all coalesced
  {
    int idx = t * 4; int q = idx >> 7; int c = idx & 127;
    *(f32x4*)&qfs[q][c]  = *(const f32x4*)(qfeat + (size_t)qbase*C_ + idx);
    *(f32x4*)&tl16[q][c] = *(const f32x4*)(ws + WS_T + idx);
    if (t < 32) *(f32x4*)&wcl[t*4] = *(const f32x4*)(W1 + 2*C_*C_ + t*4);
  }
  __syncthreads();

  // 1/max(||q||, eps)
  if (t < 128){
    int q = t >> 3; int c0 = (t & 7) * 16;
    float s = 0.f;
    #pragma unroll
    for (int m = 0; m < 16; ++m){ float v = qfs[q][c0+m]; s = fmaf(v, v, s); }
    s += __shfl_xor(s, 1); s += __shfl_xor(s, 2); s += __shfl_xor(s, 4);
    if ((t & 7) == 0) rqn[q] = 1.f / fmaxf(sqrtf(s), 1e-8f);
  }

  const int fr = lane & 15;
  const int fg = lane >> 4;
  const int ocol = wv*16 + fr;

  // A-fragments of qf; B-fragments of W2/Wq coalesced from pack
  s16x8 qfr[4], w2f[4], wqf[4];
  #pragma unroll
  for (int ks = 0; ks < 4; ++ks){
    const int c0 = ks*32 + fg*8;
    f32x4 a = *(const f32x4*)&qfs[fr][c0];
    f32x4 b = *(const f32x4*)&qfs[fr][c0+4];
    s16x8 v;
    v[0]=f2bf(a[0]); v[1]=f2bf(a[1]); v[2]=f2bf(a[2]); v[3]=f2bf(a[3]);
    v[4]=f2bf(b[0]); v[5]=f2bf(b[1]); v[6]=f2bf(b[2]); v[7]=f2bf(b[3]);
    qfr[ks] = v;
    w2f[ks] = *(const s16x8*)&pack[((wv*4 + ks)*64 + lane)*8];
    wqf[ks] = *(const s16x8*)&pack[16384 + ((wv*4 + ks)*64 + lane)*8];
  }
  const float b2v = b2[ocol];
  __syncthreads();   // rqn ready; all qfs reads done

  // qW = qf @ Wq
  {
    f32x4 dq = {0.f,0.f,0.f,0.f};
    #pragma unroll
    for (int ks = 0; ks < 4; ++ks)
      dq = __builtin_amdgcn_mfma_f32_16x16x32_bf16(qfr[ks], wqf[ks], dq, 0,0,0);
    #pragma unroll
    for (int r = 0; r < 4; ++r) qw[fg*4 + r][ocol] = dq[r];
  }
  // cos = (qf @ pn^T) * rqn   (wave 0)
  if (wv == 0){
    s16x8 pnf[4];
    #pragma unroll
    for (int ks = 0; ks < 4; ++ks)
      pnf[ks] = *(const s16x8*)&pack[32768 + (ks*64 + lane)*8];
    f32x4 dc = {0.f,0.f,0.f,0.f};
    #pragma unroll
    for (int ks = 0; ks < 4; ++ks)
      dc = __builtin_amdgcn_mfma_f32_16x16x32_bf16(qfr[ks], pnf[ks], dc, 0,0,0);
    #pragma unroll
    for (int r = 0; r < 4; ++r){
      const int q = fg*4 + r;
      const float cv = dc[r] * rqn[q];
      cosl[q][fr] = cv;
      __builtin_nontemporal_store(cv, &out_cos[(size_t)(qbase + q)*NC_ + fr]);
    }
  }
  BAR_LGKM();        // qw/cosl ready; qfs dead -> hfrag live; out_cos stores NOT drained

  // phase-A constants: wave wv -> (ksA = wv&3, qsel = wv>>2); lane -> (class na, k-group ga)
  const int na  = lane & 15;
  const int ga  = lane >> 4;
  const int ksA = wv & 3;
  const int qsel = wv >> 2;
  const int k0  = ksA*32 + ga*8;
  const f32x4 tA = *(const f32x4*)&tl16[na][k0];
  const f32x4 tB = *(const f32x4*)&tl16[na][k0+4];
  const f32x4 wA = *(const f32x4*)&wcl[k0];
  const f32x4 wB = *(const f32x4*)&wcl[k0+4];
  char* hbase = un;

  auto do_A = [&](int c){
    const int q = c*2 + qsel;
    const f32x4 q1 = *(const f32x4*)&qw[q][k0];
    const f32x4 q2 = *(const f32x4*)&qw[q][k0+4];
    const float cv = cosl[q][na];
    s16x8 hv;
    #pragma unroll
    for (int j = 0; j < 4; ++j){
      float h = fmaf(cv, wA[j], q1[j] + tA[j]);
      hv[j] = f2bf(fmaxf(h, 0.f));
    }
    #pragma unroll
    for (int j = 0; j < 4; ++j){
      float h = fmaf(cv, wB[j], q2[j] + tB[j]);
      hv[4+j] = f2bf(fmaxf(h, 0.f));
    }
    *(s16x8*)(hbase + (c&1)*8192 + qsel*4096 + ksA*1024 + lane*16) = hv;  // b128, conflict-free
  };

  auto do_B = [&](int c){
    #pragma unroll
    for (int qq = 0; qq < 2; ++qq){
      const char* hb = hbase + (c&1)*8192 + qq*4096 + lane*16;
      s16x8 a0 = *(const s16x8*)(hb);
      s16x8 a1 = *(const s16x8*)(hb + 1024);
      s16x8 a2 = *(const s16x8*)(hb + 2048);
      s16x8 a3 = *(const s16x8*)(hb + 3072);
      f32x4 acc = {b2v, b2v, b2v, b2v};
      acc = __builtin_amdgcn_mfma_f32_16x16x32_bf16(a0, w2f[0], acc, 0,0,0);
      acc = __builtin_amdgcn_mfma_f32_16x16x32_bf16(a1, w2f[1], acc, 0,0,0);
      acc = __builtin_amdgcn_mfma_f32_16x16x32_bf16(a2, w2f[2], acc, 0,0,0);
      acc = __builtin_amdgcn_mfma_f32_16x16x32_bf16(a3, w2f[3], acc, 0,0,0);
      const size_t qout = (size_t)(qbase + c*2 + qq) * (NC_*C_);
      #pragma unroll
      for (int r = 0; r < 4; ++r)
        __builtin_nontemporal_store(acc[r], &out[qout + (fg*4 + r)*C_ + ocol]);
    }
  };

  do_A(0);
  BAR_LGKM();
  #pragma unroll
  for (int c = 0; c < 8; ++c){
    do_B(c);
    if (c < 7) do_A(c + 1);
    BAR_LGKM();      // LDS-only: stores from do_B remain in flight
  }
}

extern "C" void kernel_launch(void* const* d_in, const int* in_sizes, int n_in,
                              void* d_out, int out_size, void* d_ws, size_t ws_size,
                              hipStream_t stream){
  const float* sf  = (const float*)d_in[0];
  const int*   lbl = (const int*)  d_in[1];
  const float* qf  = (const float*)d_in[2];
  const float* W1  = (const float*)d_in[3];
  const float* b1  = (const float*)d_in[4];
  const float* W2  = (const float*)d_in[5];
  const float* b2  = (const float*)d_in[6];
  float* ws  = (float*)d_ws;
  float* out = (float*)d_out;

  proto_part<<<256, 128, 0, stream>>>(sf, lbl, ws);
  prep2<<<1, 512, 0, stream>>>(W1, b1, W2, ws);
  fused_main<<<NBLK, 512, 0, stream>>>(qf, W1, b2, ws, out);
}